// Round 1
// baseline (742.877 us; speedup 1.0000x reference)
//
#include <hip/hip_runtime.h>
#include <math.h>

#define NSPEC 7
#define NMOL 1024
#define APM 48
#define NATOMS (NMOL * APM)   // 49152
#define FDIM 384
#define MT 32                 // atoms per tile

// ws layout (ints): [0..7) species counts (slot 7 pad), [8 ..) bucket[NSPEC][NATOMS]
// ws bytes needed: (8 + 7*49152)*4 ~= 1.32 MB

__device__ __forceinline__ float celu01(float x) {
    return x > 0.0f ? x : 0.1f * expm1f(x * 10.0f);
}

// ---------------- bucketing ----------------
__global__ void bucket_kernel(const int* __restrict__ species,
                              int* __restrict__ g_cnt,
                              int* __restrict__ bucket) {
    __shared__ int l_cnt[NSPEC];
    __shared__ int l_base[NSPEC];
    int t = threadIdx.x;
    if (t < NSPEC) l_cnt[t] = 0;
    __syncthreads();
    int i = blockIdx.x * blockDim.x + t;   // grid covers NATOMS exactly
    int s = species[i];
    int lpos = atomicAdd(&l_cnt[s], 1);
    __syncthreads();
    if (t < NSPEC) l_base[t] = atomicAdd(&g_cnt[t], l_cnt[t]);
    __syncthreads();
    bucket[s * NATOMS + l_base[s] + lpos] = i;
}

// ---------------- fused MLP ----------------
// Generic dense layer: out[m][n] = celu(bias[n] + sum_k in[m][k]*W[n][k])
// Thread map: tm = tid&7 (8 m-groups of 4), tn = tid>>3 (n-group of 8).
// arow[i] points at row m=tm*4+i of the input (global or LDS), K4 float4s long.
// Output written to LDS out4 with row stride SOUT (float4 units, odd for bank spread).
template <int K4, int N, int SOUT>
__device__ __forceinline__ void dense_layer(const float4* const* arow,
                                            float4* __restrict__ out4,
                                            const float* __restrict__ W,
                                            const float* __restrict__ bias,
                                            int tm, int tn) {
    if (tn * 8 < N) {
        const float4* wrow[8];
#pragma unroll
        for (int j = 0; j < 8; ++j)
            wrow[j] = (const float4*)(W + (size_t)(tn * 8 + j) * (K4 * 4));

        float acc[4][8];
#pragma unroll
        for (int i = 0; i < 4; ++i)
#pragma unroll
            for (int j = 0; j < 8; ++j) acc[i][j] = 0.0f;

        for (int k = 0; k < K4; ++k) {
            float4 a[4];
#pragma unroll
            for (int i = 0; i < 4; ++i) a[i] = arow[i][k];
            float4 w[8];
#pragma unroll
            for (int j = 0; j < 8; ++j) w[j] = wrow[j][k];
#pragma unroll
            for (int i = 0; i < 4; ++i) {
#pragma unroll
                for (int j = 0; j < 8; ++j) {
                    acc[i][j] += a[i].x * w[j].x;
                    acc[i][j] += a[i].y * w[j].y;
                    acc[i][j] += a[i].z * w[j].z;
                    acc[i][j] += a[i].w * w[j].w;
                }
            }
        }

        float bj[8];
#pragma unroll
        for (int j = 0; j < 8; ++j) bj[j] = bias[tn * 8 + j];

#pragma unroll
        for (int i = 0; i < 4; ++i) {
            int m = tm * 4 + i;
            float4 v0, v1;
            v0.x = celu01(acc[i][0] + bj[0]);
            v0.y = celu01(acc[i][1] + bj[1]);
            v0.z = celu01(acc[i][2] + bj[2]);
            v0.w = celu01(acc[i][3] + bj[3]);
            v1.x = celu01(acc[i][4] + bj[4]);
            v1.y = celu01(acc[i][5] + bj[5]);
            v1.z = celu01(acc[i][6] + bj[6]);
            v1.w = celu01(acc[i][7] + bj[7]);
            out4[m * SOUT + tn * 2 + 0] = v0;
            out4[m * SOUT + tn * 2 + 1] = v1;
        }
    }
}

__global__ __launch_bounds__(256, 2) void mlp_kernel(
    const float* __restrict__ aev,
    const float* __restrict__ W1, const float* __restrict__ b1,
    const float* __restrict__ W2, const float* __restrict__ b2,
    const float* __restrict__ W3, const float* __restrict__ b3,
    const float* __restrict__ W4, const float* __restrict__ b4,
    const int* __restrict__ g_cnt, const int* __restrict__ bucket,
    float* __restrict__ out) {
    int s = blockIdx.y;
    int cnt = g_cnt[s];
    int base = blockIdx.x * MT;
    if (base >= cnt) return;

    // LDS ping-pong. Row strides in float4 units, odd => bank-conflict-free
    // for the 8-unique-row access pattern.
    __shared__ float4 hA[MT * 49];  // h2 (stride 49)
    __shared__ float4 hB[MT * 65];  // h1 (stride 65), then h3 (stride 41)
    __shared__ int s_atom[MT];

    int t = threadIdx.x;
    if (t < MT) {
        int idx = base + t;
        if (idx >= cnt) idx = cnt - 1;  // pad with duplicate; no store later
        s_atom[t] = bucket[s * NATOMS + idx];
    }
    __syncthreads();

    int tm = t & 7;
    int tn = t >> 3;

    // ---- layer 1: 384 -> 256, input gathered from global aev ----
    {
        const float4* arow[4];
#pragma unroll
        for (int i = 0; i < 4; ++i)
            arow[i] = (const float4*)(aev + (size_t)s_atom[tm * 4 + i] * FDIM);
        dense_layer<96, 256, 65>(arow, hB, W1 + (size_t)s * 256 * 384,
                                 b1 + s * 256, tm, tn);
    }
    __syncthreads();

    // ---- layer 2: 256 -> 192 ----
    {
        const float4* arow[4];
#pragma unroll
        for (int i = 0; i < 4; ++i) arow[i] = hB + (tm * 4 + i) * 65;
        dense_layer<64, 192, 49>(arow, hA, W2 + (size_t)s * 192 * 256,
                                 b2 + s * 192, tm, tn);
    }
    __syncthreads();

    // ---- layer 3: 192 -> 160, output into hB with stride 41 ----
    {
        const float4* arow[4];
#pragma unroll
        for (int i = 0; i < 4; ++i) arow[i] = hA + (tm * 4 + i) * 49;
        dense_layer<48, 160, 41>(arow, hB, W3 + (size_t)s * 160 * 192,
                                 b3 + s * 160, tm, tn);
    }
    __syncthreads();

    // ---- layer 4: 160 -> 1, then scatter-add per molecule ----
    {
        int m = t >> 3;
        int sub = t & 7;
        const float4* w4 = (const float4*)(W4 + (size_t)s * 160);
        const float4* h3 = hB + m * 41;
        float p = 0.0f;
#pragma unroll
        for (int c = 0; c < 5; ++c) {
            float4 h = h3[sub + c * 8];
            float4 w = w4[sub + c * 8];
            p += h.x * w.x + h.y * w.y + h.z * w.z + h.w * w.w;
        }
        p += __shfl_down(p, 4, 8);
        p += __shfl_down(p, 2, 8);
        p += __shfl_down(p, 1, 8);
        if (sub == 0 && base + m < cnt) {
            float e = p + b4[s];
            int atom = s_atom[m];
            atomicAdd(&out[atom / APM], e);
        }
    }
}

extern "C" void kernel_launch(void* const* d_in, const int* in_sizes, int n_in,
                              void* d_out, int out_size, void* d_ws, size_t ws_size,
                              hipStream_t stream) {
    const int* species = (const int*)d_in[0];
    const float* aev = (const float*)d_in[1];
    const float* W1 = (const float*)d_in[2];
    const float* b1 = (const float*)d_in[3];
    const float* W2 = (const float*)d_in[4];
    const float* b2 = (const float*)d_in[5];
    const float* W3 = (const float*)d_in[6];
    const float* b3 = (const float*)d_in[7];
    const float* W4 = (const float*)d_in[8];
    const float* b4 = (const float*)d_in[9];
    float* out = (float*)d_out;

    int* g_cnt = (int*)d_ws;
    int* bucket = g_cnt + 8;

    hipMemsetAsync(d_out, 0, NMOL * sizeof(float), stream);
    hipMemsetAsync(g_cnt, 0, 8 * sizeof(int), stream);

    bucket_kernel<<<NATOMS / 256, 256, 0, stream>>>(species, g_cnt, bucket);

    dim3 grid(NATOMS / MT, NSPEC);
    mlp_kernel<<<grid, 256, 0, stream>>>(aev, W1, b1, W2, b2, W3, b3, W4, b4,
                                         g_cnt, bucket, out);
}

// Round 2
// 231.505 us; speedup vs baseline: 3.2089x; 3.2089x over previous
//
#include <hip/hip_runtime.h>
#include <math.h>

#define NSPEC 7
#define NMOL 1024
#define APM 48
#define NATOMS (NMOL * APM)   // 49152
#define FDIM 384

typedef unsigned short u16;
typedef unsigned int u32;
typedef __attribute__((ext_vector_type(8))) short short8;
typedef __attribute__((ext_vector_type(4))) float floatx4;

// Packed-weight geometry: [s][ntile][kg][lane(64)][8] bf16, frag = 16B/lane.
#define W1_ELEMS_PER_S (16 * 12 * 64 * 8)   // 98304
#define W2_ELEMS_PER_S (12 * 8 * 64 * 8)    // 49152
#define W3_ELEMS_PER_S (10 * 6 * 64 * 8)    // 30720
#define T1 (NSPEC * 16 * 12 * 64)           // 86016 pack threads
#define T2 (NSPEC * 12 * 8 * 64)            // 43008
#define T3 (NSPEC * 10 * 6 * 64)            // 26880

// ws layout (bytes): g_cnt[8] @0, w1p @32 (1376256), w2p (+688128), w3p (+430080),
// bucket u16[7*49152] (+688128). Total ~3.2 MB.
#define WS_W1_OFF 32
#define WS_W2_OFF (WS_W1_OFF + 1376256)
#define WS_W3_OFF (WS_W2_OFF + 688128)
#define WS_BKT_OFF (WS_W3_OFF + 430080)

__device__ __forceinline__ float celu01(float x) {
    return x > 0.0f ? x : 0.1f * expm1f(x * 10.0f);
}

__device__ __forceinline__ u16 bfr(float f) {  // fp32 -> bf16 RNE
    u32 u = __float_as_uint(f);
    u += 0x7fffu + ((u >> 16) & 1u);
    return (u16)(u >> 16);
}

__device__ __forceinline__ float bf2f(short s) {
    return __uint_as_float(((u32)(u16)s) << 16);
}

union U8 { short8 v; u16 u[8]; };

// ---------------- bucketing (ushort atom ids) ----------------
__global__ void bucket_kernel(const int* __restrict__ species,
                              int* __restrict__ g_cnt,
                              u16* __restrict__ bucket) {
    __shared__ int l_cnt[NSPEC];
    __shared__ int l_base[NSPEC];
    int t = threadIdx.x;
    if (t < NSPEC) l_cnt[t] = 0;
    __syncthreads();
    int i = blockIdx.x * blockDim.x + t;
    int s = species[i];
    int lpos = atomicAdd(&l_cnt[s], 1);
    __syncthreads();
    if (t < NSPEC) l_base[t] = atomicAdd(&g_cnt[t], l_cnt[t]);
    __syncthreads();
    bucket[s * NATOMS + l_base[s] + lpos] = (u16)i;
}

// ---------------- weight pack: fp32 [s][n][k] -> bf16 frag-ordered ----------------
__global__ void pack_kernel(const float* __restrict__ W1, const float* __restrict__ W2,
                            const float* __restrict__ W3,
                            u16* __restrict__ w1p, u16* __restrict__ w2p,
                            u16* __restrict__ w3p) {
    int tid = blockIdx.x * 256 + threadIdx.x;
    const float* W;
    u16* dst;
    int KGS, NTILES, idx;
    if (tid < T1) { W = W1; dst = w1p; KGS = 12; NTILES = 16; idx = tid; }
    else if (tid < T1 + T2) { W = W2; dst = w2p; KGS = 8; NTILES = 12; idx = tid - T1; }
    else { W = W3; dst = w3p; KGS = 6; NTILES = 10; idx = tid - (T1 + T2); }
    int lane = idx & 63;
    int q = idx >> 6;
    int kg = q % KGS; q /= KGS;
    int t2 = q % NTILES;
    int s = q / NTILES;
    int K = KGS * 32;
    int n = t2 * 16 + (lane & 15);
    int k0 = kg * 32 + ((lane >> 4) & 3) * 8;
    const float* src = W + (size_t)(s * NTILES * 16 + n) * K + k0;
    U8 x;
#pragma unroll
    for (int j = 0; j < 8; ++j) x.u[j] = bfr(src[j]);
    *reinterpret_cast<short8*>(dst + (size_t)idx * 8) = x.v;
}

// ---------------- MFMA layers ----------------
template <int KGS, int IST>
__device__ __forceinline__ void load_a_lds(const u16* __restrict__ inbuf, short8* af, int lane) {
    int m = lane & 15, kg4 = lane >> 4;
#pragma unroll
    for (int kg = 0; kg < KGS; ++kg)
        af[kg] = *reinterpret_cast<const short8*>(inbuf + (size_t)m * IST + kg * 32 + kg4 * 8);
}

template <int KGS, int NTILES, int OST>
__device__ __forceinline__ void run_layer(const short8* af, const u16* __restrict__ wsp,
                                          const float* __restrict__ bias,
                                          u16* __restrict__ outbuf, int lane) {
    const int nl = lane & 15, kg4 = lane >> 4;
#pragma unroll 2
    for (int t = 0; t < NTILES; ++t) {
        floatx4 acc = {0.f, 0.f, 0.f, 0.f};
        const u16* wb = wsp + (size_t)(t * KGS) * 512 + (size_t)lane * 8;
        short8 bf[KGS];
#pragma unroll
        for (int kg = 0; kg < KGS; ++kg)
            bf[kg] = *reinterpret_cast<const short8*>(wb + kg * 512);
#pragma unroll
        for (int kg = 0; kg < KGS; ++kg)
            acc = __builtin_amdgcn_mfma_f32_16x16x32_bf16(af[kg], bf[kg], acc, 0, 0, 0);
        float bn = bias[t * 16 + nl];
#pragma unroll
        for (int r = 0; r < 4; ++r) {
            float h = celu01(acc[r] + bn);
            outbuf[(kg4 * 4 + r) * OST + t * 16 + nl] = bfr(h);
        }
    }
}

__global__ __launch_bounds__(256, 2) void mlp_kernel(
    const float* __restrict__ aev,
    const u16* __restrict__ w1p, const u16* __restrict__ w2p, const u16* __restrict__ w3p,
    const float* __restrict__ b1, const float* __restrict__ b2, const float* __restrict__ b3,
    const float* __restrict__ W4, const float* __restrict__ b4,
    const int* __restrict__ g_cnt, const u16* __restrict__ bucket,
    float* __restrict__ out) {
    int s = blockIdx.y;
    int cnt = g_cnt[s];
    int base = blockIdx.x * 64;
    if (base >= cnt) return;

    // Per-wave private LDS activation buffers (no cross-wave sharing).
    // Row strides 264/200 u16 (16B-aligned, odd-dword => ~2-way max conflicts).
    __shared__ __align__(16) u16 bufA[4][16 * 264];  // h1 (256 wide), then h3 (160)
    __shared__ __align__(16) u16 bufB[4][16 * 200];  // h2 (192 wide)
    __shared__ int s_atom[64];

    int t = threadIdx.x;
    if (t < 64) {
        int idx = base + t;
        if (idx >= cnt) idx = cnt - 1;  // pad with duplicate; store suppressed
        s_atom[t] = (int)bucket[s * NATOMS + idx];
    }
    __syncthreads();

    int w = t >> 6, lane = t & 63;
    int nl = lane & 15, kg4 = lane >> 4;
    u16* bA = &bufA[w][0];
    u16* bB = &bufB[w][0];

    // ---- layer 1: 384 -> 256. A from global fp32 aev, converted in-register ----
    short8 af1[12];
    {
        int atom = s_atom[w * 16 + nl];
        const float* ar = aev + (size_t)atom * FDIM;
#pragma unroll
        for (int kg = 0; kg < 12; ++kg) {
            const float4* p = (const float4*)(ar + kg * 32 + kg4 * 8);
            float4 a = p[0], b = p[1];
            U8 x;
            x.u[0] = bfr(a.x); x.u[1] = bfr(a.y); x.u[2] = bfr(a.z); x.u[3] = bfr(a.w);
            x.u[4] = bfr(b.x); x.u[5] = bfr(b.y); x.u[6] = bfr(b.z); x.u[7] = bfr(b.w);
            af1[kg] = x.v;
        }
    }
    run_layer<12, 16, 264>(af1, w1p + (size_t)s * W1_ELEMS_PER_S, b1 + s * 256, bA, lane);
    __syncthreads();

    // ---- layer 2: 256 -> 192 ----
    short8 af2[8];
    load_a_lds<8, 264>(bA, af2, lane);
    run_layer<8, 12, 200>(af2, w2p + (size_t)s * W2_ELEMS_PER_S, b2 + s * 192, bB, lane);
    __syncthreads();

    // ---- layer 3: 192 -> 160 ----
    short8 af3[6];
    load_a_lds<6, 200>(bB, af3, lane);
    run_layer<6, 10, 264>(af3, w3p + (size_t)s * W3_ELEMS_PER_S, b3 + s * 160, bA, lane);
    __syncthreads();

    // ---- layer 4: 160 -> 1 (fp32 VALU) + molecule scatter-add ----
    {
        int m = lane >> 2, q = lane & 3;
        const u16* h = bA + m * 264 + q * 40;
        const float* w4s = W4 + s * 160 + q * 40;
        float p = 0.f;
#pragma unroll
        for (int c = 0; c < 5; ++c) {
            short8 hv = *reinterpret_cast<const short8*>(h + c * 8);
            const float4* wp4 = (const float4*)(w4s + c * 8);
            float4 wa = wp4[0], wb = wp4[1];
            p += bf2f(hv[0]) * wa.x + bf2f(hv[1]) * wa.y + bf2f(hv[2]) * wa.z + bf2f(hv[3]) * wa.w;
            p += bf2f(hv[4]) * wb.x + bf2f(hv[5]) * wb.y + bf2f(hv[6]) * wb.z + bf2f(hv[7]) * wb.w;
        }
        p += __shfl_down(p, 2, 4);
        p += __shfl_down(p, 1, 4);
        if (q == 0) {
            int idx = base + w * 16 + m;
            if (idx < cnt) {
                int atom = s_atom[w * 16 + m];
                atomicAdd(&out[atom / APM], p + b4[s]);
            }
        }
    }
}

extern "C" void kernel_launch(void* const* d_in, const int* in_sizes, int n_in,
                              void* d_out, int out_size, void* d_ws, size_t ws_size,
                              hipStream_t stream) {
    const int* species = (const int*)d_in[0];
    const float* aev = (const float*)d_in[1];
    const float* W1 = (const float*)d_in[2];
    const float* b1 = (const float*)d_in[3];
    const float* W2 = (const float*)d_in[4];
    const float* b2 = (const float*)d_in[5];
    const float* W3 = (const float*)d_in[6];
    const float* b3 = (const float*)d_in[7];
    const float* W4 = (const float*)d_in[8];
    const float* b4 = (const float*)d_in[9];
    float* out = (float*)d_out;

    unsigned char* wsb = (unsigned char*)d_ws;
    int* g_cnt = (int*)wsb;
    u16* w1p = (u16*)(wsb + WS_W1_OFF);
    u16* w2p = (u16*)(wsb + WS_W2_OFF);
    u16* w3p = (u16*)(wsb + WS_W3_OFF);
    u16* bucket = (u16*)(wsb + WS_BKT_OFF);

    hipMemsetAsync(d_out, 0, NMOL * sizeof(float), stream);
    hipMemsetAsync(g_cnt, 0, 8 * sizeof(int), stream);

    pack_kernel<<<(T1 + T2 + T3) / 256, 256, 0, stream>>>(W1, W2, W3, w1p, w2p, w3p);
    bucket_kernel<<<NATOMS / 256, 256, 0, stream>>>(species, g_cnt, bucket);

    dim3 grid(NATOMS / 64, NSPEC);
    mlp_kernel<<<grid, 256, 0, stream>>>(aev, w1p, w2p, w3p, b1, b2, b3, W4, b4,
                                         g_cnt, bucket, out);
}

// Round 3
// 193.440 us; speedup vs baseline: 3.8404x; 1.1968x over previous
//
#include <hip/hip_runtime.h>
#include <math.h>

#define NSPEC 7
#define NMOL 1024
#define APM 48
#define NATOMS (NMOL * APM)   // 49152
#define FDIM 384

typedef unsigned short u16;
typedef unsigned int u32;
typedef __attribute__((ext_vector_type(8))) short short8;
typedef __attribute__((ext_vector_type(4))) float floatx4;

// Packed-weight geometry: [s][ntile][kg][lane(64)][8] bf16, frag = 16B/lane.
#define W1_ELEMS_PER_S (16 * 12 * 64 * 8)   // 98304
#define W2_ELEMS_PER_S (12 * 8 * 64 * 8)    // 49152
#define W3_ELEMS_PER_S (10 * 6 * 64 * 8)    // 30720
#define T1 (NSPEC * 16 * 12 * 64)           // 86016 pack threads
#define T2 (NSPEC * 12 * 8 * 64)            // 43008
#define T3 (NSPEC * 10 * 6 * 64)            // 26880
#define BUCKET_BLOCKS (NATOMS / 256)        // 192
#define PACK_BLOCKS ((T1 + T2 + T3) / 256)  // 609

// ws layout (bytes): g_cnt[8] @0, w1p @32, w2p, w3p, bucket u16[7*NATOMS].
#define WS_W1_OFF 32
#define WS_W2_OFF (WS_W1_OFF + 1376256)
#define WS_W3_OFF (WS_W2_OFF + 688128)
#define WS_BKT_OFF (WS_W3_OFF + 430080)

#define BUFST 264   // LDS activation row stride in u16 (16B-aligned)

__device__ __forceinline__ float celu01(float x) {
    return x > 0.0f ? x : 0.1f * expm1f(x * 10.0f);
}

__device__ __forceinline__ u16 bfr(float f) {  // fp32 -> bf16 RNE
    u32 u = __float_as_uint(f);
    u += 0x7fffu + ((u >> 16) & 1u);
    return (u16)(u >> 16);
}

__device__ __forceinline__ float bf2f(short s) {
    return __uint_as_float(((u32)(u16)s) << 16);
}

union U8 { short8 v; u16 u[8]; };

// ---------------- prep: bucket + weight pack, fused ----------------
__global__ void prep_kernel(const int* __restrict__ species,
                            int* __restrict__ g_cnt, u16* __restrict__ bucket,
                            const float* __restrict__ W1, const float* __restrict__ W2,
                            const float* __restrict__ W3,
                            u16* __restrict__ w1p, u16* __restrict__ w2p,
                            u16* __restrict__ w3p) {
    int t = threadIdx.x;
    if (blockIdx.x < BUCKET_BLOCKS) {
        __shared__ int l_cnt[NSPEC];
        __shared__ int l_base[NSPEC];
        if (t < NSPEC) l_cnt[t] = 0;
        __syncthreads();
        int i = blockIdx.x * 256 + t;
        int s = species[i];
        int lpos = atomicAdd(&l_cnt[s], 1);
        __syncthreads();
        if (t < NSPEC) l_base[t] = atomicAdd(&g_cnt[t], l_cnt[t]);
        __syncthreads();
        bucket[s * NATOMS + l_base[s] + lpos] = (u16)i;
    } else {
        int tid = (blockIdx.x - BUCKET_BLOCKS) * 256 + t;
        const float* W;
        u16* dst;
        int KGS, NTILES, idx;
        if (tid < T1) { W = W1; dst = w1p; KGS = 12; NTILES = 16; idx = tid; }
        else if (tid < T1 + T2) { W = W2; dst = w2p; KGS = 8; NTILES = 12; idx = tid - T1; }
        else { W = W3; dst = w3p; KGS = 6; NTILES = 10; idx = tid - (T1 + T2); }
        int lane = idx & 63;
        int q = idx >> 6;
        int kg = q % KGS; q /= KGS;
        int t2 = q % NTILES;
        int s = q / NTILES;
        int K = KGS * 32;
        int n = t2 * 16 + (lane & 15);
        int k0 = kg * 32 + ((lane >> 4) & 3) * 8;
        const float* src = W + (size_t)(s * NTILES * 16 + n) * K + k0;
        U8 x;
#pragma unroll
        for (int j = 0; j < 8; ++j) x.u[j] = bfr(src[j]);
        *reinterpret_cast<short8*>(dst + (size_t)idx * 8) = x.v;
    }
}

// ---------------- MFMA layer: 2 m-tiles (32 atoms), dbuf'd B ----------------
template <int KGS, int NTILES>
__device__ __forceinline__ void run_layer(const short8* af0, const short8* af1,
                                          const u16* __restrict__ wsp,
                                          const float* __restrict__ bias,
                                          u16* __restrict__ outbuf, int lane) {
    const int nl = lane & 15, kg4 = lane >> 4;
    short8 bcur[KGS], bnext[KGS];
    {
        const u16* wb = wsp + (size_t)lane * 8;
#pragma unroll
        for (int kg = 0; kg < KGS; ++kg)
            bcur[kg] = *reinterpret_cast<const short8*>(wb + kg * 512);
    }
#pragma unroll
    for (int t = 0; t < NTILES; ++t) {
        if (t + 1 < NTILES) {
            const u16* wb = wsp + (size_t)((t + 1) * KGS) * 512 + (size_t)lane * 8;
#pragma unroll
            for (int kg = 0; kg < KGS; ++kg)
                bnext[kg] = *reinterpret_cast<const short8*>(wb + kg * 512);
        }
        floatx4 acc0 = {0.f, 0.f, 0.f, 0.f};
        floatx4 acc1 = {0.f, 0.f, 0.f, 0.f};
#pragma unroll
        for (int kg = 0; kg < KGS; ++kg) {
            acc0 = __builtin_amdgcn_mfma_f32_16x16x32_bf16(af0[kg], bcur[kg], acc0, 0, 0, 0);
            acc1 = __builtin_amdgcn_mfma_f32_16x16x32_bf16(af1[kg], bcur[kg], acc1, 0, 0, 0);
        }
        float bn = bias[t * 16 + nl];
#pragma unroll
        for (int r = 0; r < 4; ++r) {
            outbuf[(kg4 * 4 + r) * BUFST + t * 16 + nl] = bfr(celu01(acc0[r] + bn));
            outbuf[(16 + kg4 * 4 + r) * BUFST + t * 16 + nl] = bfr(celu01(acc1[r] + bn));
        }
#pragma unroll
        for (int kg = 0; kg < KGS; ++kg) bcur[kg] = bnext[kg];
    }
}

template <int KGS>
__device__ __forceinline__ void load_a_lds(const u16* __restrict__ buf,
                                           short8* af0, short8* af1, int lane) {
    int nl = lane & 15, kg4 = lane >> 4;
#pragma unroll
    for (int kg = 0; kg < KGS; ++kg) {
        af0[kg] = *reinterpret_cast<const short8*>(buf + (size_t)nl * BUFST + kg * 32 + kg4 * 8);
        af1[kg] = *reinterpret_cast<const short8*>(buf + (size_t)(16 + nl) * BUFST + kg * 32 + kg4 * 8);
    }
}

__global__ __launch_bounds__(128, 2) void mlp_kernel(
    const float* __restrict__ aev,
    const u16* __restrict__ w1p, const u16* __restrict__ w2p, const u16* __restrict__ w3p,
    const float* __restrict__ b1, const float* __restrict__ b2, const float* __restrict__ b3,
    const float* __restrict__ W4, const float* __restrict__ b4,
    const int* __restrict__ g_cnt, const u16* __restrict__ bucket,
    float* __restrict__ out) {
    int s = blockIdx.y;
    int cnt = g_cnt[s];
    int w = threadIdx.x >> 6, lane = threadIdx.x & 63;
    int base = blockIdx.x * 64 + w * 32;   // this wave's 32 atoms
    if (base >= cnt) return;

    // One wave-private LDS buffer, reused across layers (A is consumed into
    // registers before outputs are written). No __syncthreads anywhere.
    __shared__ __align__(16) u16 bufs[2][32 * BUFST];  // 33792 B/block
    u16* buf = &bufs[w][0];

    int nl = lane & 15, kg4 = lane >> 4;

    // ---- layer 1: 384 -> 256. A from global fp32 aev, converted in-register ----
    short8 af0[12], af1[12];
    {
        int i0 = base + nl;       if (i0 >= cnt) i0 = cnt - 1;
        int i1 = base + 16 + nl;  if (i1 >= cnt) i1 = cnt - 1;
        int a0 = (int)bucket[s * NATOMS + i0];
        int a1 = (int)bucket[s * NATOMS + i1];
        const float* ar0 = aev + (size_t)a0 * FDIM;
        const float* ar1 = aev + (size_t)a1 * FDIM;
#pragma unroll
        for (int kg = 0; kg < 12; ++kg) {
            const float4* p0 = (const float4*)(ar0 + kg * 32 + kg4 * 8);
            const float4* p1 = (const float4*)(ar1 + kg * 32 + kg4 * 8);
            float4 a = p0[0], b = p0[1];
            float4 c = p1[0], d = p1[1];
            U8 x, y;
            x.u[0] = bfr(a.x); x.u[1] = bfr(a.y); x.u[2] = bfr(a.z); x.u[3] = bfr(a.w);
            x.u[4] = bfr(b.x); x.u[5] = bfr(b.y); x.u[6] = bfr(b.z); x.u[7] = bfr(b.w);
            y.u[0] = bfr(c.x); y.u[1] = bfr(c.y); y.u[2] = bfr(c.z); y.u[3] = bfr(c.w);
            y.u[4] = bfr(d.x); y.u[5] = bfr(d.y); y.u[6] = bfr(d.z); y.u[7] = bfr(d.w);
            af0[kg] = x.v;
            af1[kg] = y.v;
        }
    }
    run_layer<12, 16>(af0, af1, w1p + (size_t)s * W1_ELEMS_PER_S, b1 + s * 256, buf, lane);

    // ---- layer 2: 256 -> 192 ----
    short8 c0[8], c1[8];
    load_a_lds<8>(buf, c0, c1, lane);
    run_layer<8, 12>(c0, c1, w2p + (size_t)s * W2_ELEMS_PER_S, b2 + s * 192, buf, lane);

    // ---- layer 3: 192 -> 160 ----
    short8 d0[6], d1[6];
    load_a_lds<6>(buf, d0, d1, lane);
    run_layer<6, 10>(d0, d1, w3p + (size_t)s * W3_ELEMS_PER_S, b3 + s * 160, buf, lane);

    // ---- layer 4: 160 -> 1 (fp32 VALU) + molecule scatter-add ----
    {
        int m = lane >> 1, q = lane & 1;       // 32 atoms, 2 lanes/atom (80 feats each)
        const u16* h = buf + (size_t)m * BUFST + q * 80;
        const float* w4s = W4 + s * 160 + q * 80;
        float p = 0.f;
#pragma unroll
        for (int c = 0; c < 10; ++c) {
            short8 hv = *reinterpret_cast<const short8*>(h + c * 8);
            const float4* wp4 = (const float4*)(w4s + c * 8);
            float4 wa = wp4[0], wb = wp4[1];
            p += bf2f(hv[0]) * wa.x + bf2f(hv[1]) * wa.y + bf2f(hv[2]) * wa.z + bf2f(hv[3]) * wa.w;
            p += bf2f(hv[4]) * wb.x + bf2f(hv[5]) * wb.y + bf2f(hv[6]) * wb.z + bf2f(hv[7]) * wb.w;
        }
        p += __shfl_down(p, 1, 2);
        int idx = base + m;
        if (q == 0 && idx < cnt) {
            int atom = (int)bucket[s * NATOMS + idx];
            atomicAdd(&out[atom / APM], p + b4[s]);
        }
    }
}

extern "C" void kernel_launch(void* const* d_in, const int* in_sizes, int n_in,
                              void* d_out, int out_size, void* d_ws, size_t ws_size,
                              hipStream_t stream) {
    const int* species = (const int*)d_in[0];
    const float* aev = (const float*)d_in[1];
    const float* W1 = (const float*)d_in[2];
    const float* b1 = (const float*)d_in[3];
    const float* W2 = (const float*)d_in[4];
    const float* b2 = (const float*)d_in[5];
    const float* W3 = (const float*)d_in[6];
    const float* b3 = (const float*)d_in[7];
    const float* W4 = (const float*)d_in[8];
    const float* b4 = (const float*)d_in[9];
    float* out = (float*)d_out;

    unsigned char* wsb = (unsigned char*)d_ws;
    int* g_cnt = (int*)wsb;
    u16* w1p = (u16*)(wsb + WS_W1_OFF);
    u16* w2p = (u16*)(wsb + WS_W2_OFF);
    u16* w3p = (u16*)(wsb + WS_W3_OFF);
    u16* bucket = (u16*)(wsb + WS_BKT_OFF);

    hipMemsetAsync(d_out, 0, NMOL * sizeof(float), stream);
    hipMemsetAsync(g_cnt, 0, 8 * sizeof(int), stream);

    prep_kernel<<<BUCKET_BLOCKS + PACK_BLOCKS, 256, 0, stream>>>(
        species, g_cnt, bucket, W1, W2, W3, w1p, w2p, w3p);

    dim3 grid(NATOMS / 64, NSPEC);
    mlp_kernel<<<grid, 128, 0, stream>>>(aev, w1p, w2p, w3p, b1, b2, b3, W4, b4,
                                         g_cnt, bucket, out);
}